// Round 5
// baseline (419.254 us; speedup 1.0000x reference)
//
#include <hip/hip_runtime.h>
#include <math.h>

#define BB 2
#define CC 256
#define NHEAD 8
#define HD 32
#define NGRP 8
#define NNTOK 32768
#define ATT_EPS 1e-6f
#define GN_EPS 1e-5f

typedef __attribute__((ext_vector_type(8))) short bfrag8;   // 8 bf16
typedef __attribute__((ext_vector_type(4))) float accf4;    // MFMA C/D 16x16

__device__ __forceinline__ float b2f(unsigned short u) {
    unsigned int x = ((unsigned int)u) << 16;
    return __uint_as_float(x);
}
__device__ __forceinline__ unsigned short f2b(float f) {
    unsigned int x = __float_as_uint(f);
    unsigned int r = x + 0x7fffu + ((x >> 16) & 1u);
    return (unsigned short)(r >> 16);
}

// ---- workspace layout (float offsets) ----
#define WS_QMT   0ull                      // bf16 [B][H][N][32]       8,388,608 f
#define WS_XNT   8388608ull                // bf16 [B][N][264]         8,650,752 f
#define WS_WST   17039360ull               // bf16 [B][H][96][264]       405,504 f
#define WS_BIAS  17444864ull               // f32  [B][H][96]              1,536 f
#define WS_PART  17446400ull               // f32 [16][64][1056]       1,081,344 f  (den aliases head)
#define WS_PART2 18527744ull               // f32 [16][4][1056]           67,584 f
#define WS_GNP   18595328ull               // f32 [B][512][16]            16,384 f
#define WS_SCALE 18611712ull
#define WS_SHIFT 18612224ull
#define WS_KSUM  18612736ull
#define WS_AMAT  18613248ull               // bf16 [B][256][256]          65,536 f
#define WS_DEN   WS_PART                   // f32 [B][H][N] = 524,288 f (part dead by then)

// ============ Kernel 1: fused transpose-to-bf16 + GN partial stats ============
// xt_g[b][n][264] = bf16(x[b][c][n]) (RAW, no normalization). GN folded into W.
__global__ __launch_bounds__(256) void xt_gn(const float* __restrict__ x,
                                             unsigned short* __restrict__ xt_g,
                                             float* __restrict__ gnp) {
    __shared__ unsigned short xt[64][264];
    __shared__ float ls[4][8], l2s[4][8];
    int b = blockIdx.y, n0 = blockIdx.x * 64, t = threadIdx.x;
    int col4 = (t & 15) * 4;
    float sg[8]  = {0.f, 0.f, 0.f, 0.f, 0.f, 0.f, 0.f, 0.f};
    float s2g[8] = {0.f, 0.f, 0.f, 0.f, 0.f, 0.f, 0.f, 0.f};
    #pragma unroll
    for (int i = 0; i < 16; ++i) {
        int c = (t >> 4) + i * 16;        // group(c) = i>>1 (compile-time)
        const float4 v = *(const float4*)(x + (size_t)(b * CC + c) * NNTOK + n0 + col4);
        sg[i >> 1]  += v.x + v.y + v.z + v.w;
        s2g[i >> 1] += v.x * v.x + v.y * v.y + v.z * v.z + v.w * v.w;
        xt[col4 + 0][c] = f2b(v.x);
        xt[col4 + 1][c] = f2b(v.y);
        xt[col4 + 2][c] = f2b(v.z);
        xt[col4 + 3][c] = f2b(v.w);
    }
    int wave = t >> 6;
    #pragma unroll
    for (int g = 0; g < 8; ++g) {
        float a = sg[g], a2 = s2g[g];
        for (int off = 32; off; off >>= 1) {
            a  += __shfl_down(a, off);
            a2 += __shfl_down(a2, off);
        }
        if ((t & 63) == 0) { ls[wave][g] = a; l2s[wave][g] = a2; }
    }
    __syncthreads();
    // store rows (valid 512B of each 528B row) — R4 verbatim
    int n = t >> 2, q = t & 3;
    const char* src = (const char*)&xt[n][0] + q * 128;
    char* dst = (char*)(xt_g + ((size_t)b * NNTOK + n0 + n) * 264) + q * 128;
    #pragma unroll
    for (int i = 0; i < 8; ++i)
        *(float4*)(dst + i * 16) = *(const float4*)(src + i * 16);
    if (t < 8)
        gnp[((size_t)b * 512 + blockIdx.x) * 16 + t] =
            ls[0][t] + ls[1][t] + ls[2][t] + ls[3][t];
    else if (t < 16)
        gnp[((size_t)b * 512 + blockIdx.x) * 16 + t] =
            l2s[0][t - 8] + l2s[1][t - 8] + l2s[2][t - 8] + l2s[3][t - 8];
}

// ============ Kernel 2: finalize GN -> per (b,c) scale/shift ============
__global__ __launch_bounds__(256) void gn_finalize(const float* __restrict__ gnp,
                                                   const float* __restrict__ gamma,
                                                   const float* __restrict__ beta,
                                                   float* __restrict__ scale,
                                                   float* __restrict__ shift) {
    __shared__ float red[16][16][2];
    __shared__ float mean_s[16], rstd_s[16];
    int t = threadIdx.x;
    {
        int bg = t >> 4, sub = t & 15;
        int b = bg >> 3, g = bg & 7;
        float s = 0.f, s2 = 0.f;
        for (int blk = sub; blk < 512; blk += 16) {
            const float* p = gnp + ((size_t)b * 512 + blk) * 16;
            s  += p[g];
            s2 += p[8 + g];
        }
        red[bg][sub][0] = s;
        red[bg][sub][1] = s2;
    }
    __syncthreads();
    if (t < 16) {
        float s = 0.f, s2 = 0.f;
        #pragma unroll
        for (int i = 0; i < 16; ++i) { s += red[t][i][0]; s2 += red[t][i][1]; }
        const float inv = 1.0f / (float)((CC / NGRP) * NNTOK);
        float m = s * inv;
        float var = s2 * inv - m * m;
        mean_s[t] = m;
        rstd_s[t] = rsqrtf(var + GN_EPS);
    }
    __syncthreads();
    for (int idx = t; idx < BB * CC; idx += 256) {
        int b = idx / CC, c = idx % CC;
        int grp = b * NGRP + c / (CC / NGRP);
        float sc = gamma[c] * rstd_s[grp];
        scale[idx] = sc;
        shift[idx] = beta[c] - mean_s[grp] * sc;
    }
}

// ============ Kernel 3: GN-folded weights Wst[b][h][96][264] + bias[b][h][96] ====
// Wst rows: 0..31 q, 32..63 k, 64..95 v. Wst = W * scale[c]; bias = W . shift.
__global__ __launch_bounds__(256) void prep_w(const float* __restrict__ wq,
                                              const float* __restrict__ wk,
                                              const float* __restrict__ wv,
                                              const float* __restrict__ scale,
                                              const float* __restrict__ shift,
                                              unsigned short* __restrict__ Wst,
                                              float* __restrict__ biasg) {
    int h = blockIdx.x, b = blockIdx.y, t = threadIdx.x;
    __shared__ float sc_s[256], sh_s[256];
    sc_s[t] = scale[b * CC + t];
    sh_s[t] = shift[b * CC + t];
    __syncthreads();
    const float* Ws[3] = {wq, wk, wv};
    unsigned short* Wd = Wst + (size_t)(b * 8 + h) * (96 * 264);
    for (int i = t; i < 96 * 264; i += 256) {
        int r = i / 264, c = i % 264;
        float v = 0.f;
        if (c < 256) v = Ws[r >> 5][(size_t)(h * 32 + (r & 31)) * CC + c] * sc_s[c];
        Wd[i] = f2b(v);
    }
    if (t < 96) {
        const float* wrow = Ws[t >> 5] + (size_t)(h * 32 + (t & 31)) * CC;
        float s = 0.f;
        for (int c = 0; c < 256; ++c) s += wrow[c] * sh_s[c];
        biasg[(b * 8 + h) * 96 + t] = s;
    }
}

// ============ Kernel 4: fused QKV MFMA + elu + ctx/ksum (no staging LDS) ========
// grid (64, 8, 2); each block: 4 token-tiles of 128. B-frags + W-frags straight
// from global (L2/L3-hot), 1-kc prefetch. Bias folded into acc init.
__global__ __launch_bounds__(256, 3) void qkv_ctx(
    const unsigned short* __restrict__ xt_g, const unsigned short* __restrict__ Wst,
    const float* __restrict__ biasg,
    unsigned short* __restrict__ qm_t, float* __restrict__ part) {
    __shared__ char kmv[64 * 272];    // km rows 0..31, v rows 32..63
    __shared__ char qs[128 * 80];     // qm [n][80B]
    __shared__ float ksp[256];
    int tg = blockIdx.x, h = blockIdx.y, b = blockIdx.z;
    int t = threadIdx.x, lane = t & 63, w = t >> 6, lr = lane & 15, lq = lane >> 4;
    const unsigned short* Wg = Wst + (size_t)(b * 8 + h) * (96 * 264);
    const unsigned short* Xg = xt_g + (size_t)b * NNTOK * 264;
    const float* bb_ = biasg + (b * 8 + h) * 96;
    int qr = w >> 1, qc = w & 1;
    accf4 cacc = (accf4){0.f, 0.f, 0.f, 0.f};
    float ks_acc = 0.f;
    int dks = t >> 3, ocks = t & 7;

    for (int tt = 0; tt < 4; ++tt) {
        const int n0 = (tg * 4 + tt) * 128;
        accf4 acc[6][2];
        #pragma unroll
        for (int mi = 0; mi < 6; ++mi) {
            float bv0 = bb_[mi * 16 + lq * 4 + 0];
            float bv1 = bb_[mi * 16 + lq * 4 + 1];
            float bv2 = bb_[mi * 16 + lq * 4 + 2];
            float bv3 = bb_[mi * 16 + lq * 4 + 3];
            #pragma unroll
            for (int ci = 0; ci < 2; ++ci)
                acc[mi][ci] = (accf4){bv0, bv1, bv2, bv3};
        }
        // prefetch kc=0 (W addressing verified in R4; X = same formula on global)
        bfrag8 wnx[6], bnx[2];
        #pragma unroll
        for (int mi = 0; mi < 6; ++mi)
            wnx[mi] = *(const bfrag8*)(Wg + (mi * 16 + lr) * 264 + lq * 8);
        #pragma unroll
        for (int ci = 0; ci < 2; ++ci)
            bnx[ci] = *(const bfrag8*)(Xg + (size_t)(n0 + w * 32 + ci * 16 + lr) * 264 + lq * 8);
        #pragma unroll
        for (int kc = 0; kc < 8; ++kc) {
            bfrag8 wcur[6], bcur[2];
            #pragma unroll
            for (int mi = 0; mi < 6; ++mi) wcur[mi] = wnx[mi];
            #pragma unroll
            for (int ci = 0; ci < 2; ++ci) bcur[ci] = bnx[ci];
            if (kc < 7) {
                #pragma unroll
                for (int mi = 0; mi < 6; ++mi)
                    wnx[mi] = *(const bfrag8*)(Wg + (mi * 16 + lr) * 264 + (kc + 1) * 32 + lq * 8);
                #pragma unroll
                for (int ci = 0; ci < 2; ++ci)
                    bnx[ci] = *(const bfrag8*)(Xg + (size_t)(n0 + w * 32 + ci * 16 + lr) * 264 + (kc + 1) * 32 + lq * 8);
            }
            #pragma unroll
            for (int mi = 0; mi < 6; ++mi)
                #pragma unroll
                for (int ci = 0; ci < 2; ++ci)
                    acc[mi][ci] = __builtin_amdgcn_mfma_f32_16x16x32_bf16(wcur[mi], bcur[ci], acc[mi][ci], 0, 0, 0);
        }
        __syncthreads();   // prev tile's LDS consumers done

        // epilogue (R4 verbatim indexing)
        #pragma unroll
        for (int mi = 0; mi < 2; ++mi)
            #pragma unroll
            for (int ci = 0; ci < 2; ++ci)
                #pragma unroll
                for (int r = 0; r < 4; ++r) {
                    int d = mi * 16 + lq * 4 + r;
                    int n = w * 32 + ci * 16 + lr;
                    float q = acc[mi][ci][r];
                    *(unsigned short*)(qs + n * 80 + d * 2) = f2b(q > 0.f ? q + 1.f : expf(q));
                }
        #pragma unroll
        for (int mi = 2; mi < 4; ++mi)
            #pragma unroll
            for (int ci = 0; ci < 2; ++ci)
                #pragma unroll
                for (int r = 0; r < 4; ++r) {
                    int d = (mi - 2) * 16 + lq * 4 + r;
                    int n = w * 32 + ci * 16 + lr;
                    float kk = acc[mi][ci][r];
                    *(unsigned short*)(kmv + d * 272 + n * 2) = f2b(kk > 0.f ? kk + 1.f : expf(kk));
                }
        #pragma unroll
        for (int mi = 4; mi < 6; ++mi)
            #pragma unroll
            for (int ci = 0; ci < 2; ++ci)
                #pragma unroll
                for (int r = 0; r < 4; ++r) {
                    int e = (mi - 4) * 16 + lq * 4 + r;
                    int n = w * 32 + ci * 16 + lr;
                    *(unsigned short*)(kmv + (32 + e) * 272 + n * 2) = f2b(acc[mi][ci][r]);
                }
        __syncthreads();

        // qm -> global (R4 verbatim)
        {
            char* qg = (char*)(qm_t + ((size_t)(b * NHEAD + h) * NNTOK + n0) * 32);
            int n = t >> 1, half = t & 1;
            const char* src = qs + n * 80 + half * 32;
            char* dst = qg + n * 64 + half * 32;
            *(float4*)dst = *(const float4*)src;
            *(float4*)(dst + 16) = *(const float4*)(src + 16);
        }
        // ctx quadrant accumulate (R4 verbatim, acc across 4 tiles)
        #pragma unroll
        for (int kk = 0; kk < 4; ++kk) {
            bfrag8 a  = *(const bfrag8*)(kmv + (qr * 16 + lr) * 272 + kk * 64 + lq * 16);
            bfrag8 bv = *(const bfrag8*)(kmv + (32 + qc * 16 + lr) * 272 + kk * 64 + lq * 16);
            cacc = __builtin_amdgcn_mfma_f32_16x16x32_bf16(a, bv, cacc, 0, 0, 0);
        }
        // ksum accumulate (R4 verbatim read pattern)
        {
            float s = 0.f;
            for (int i = 0; i < 16; ++i)
                s += b2f(*(const unsigned short*)(kmv + dks * 272 + (ocks * 16 + i) * 2));
            ks_acc += s;
        }
        __syncthreads();   // protect kmv/qs before next tile's epilogue
    }

    const size_t rec = (size_t)((b * NHEAD + h) * 64 + tg) * 1056;
    #pragma unroll
    for (int r = 0; r < 4; ++r) {
        int d = qr * 16 + lq * 4 + r, e = qc * 16 + lr;
        part[rec + d * 32 + e] = cacc[r];
    }
    ksp[dks * 8 + ocks] = ks_acc;
    __syncthreads();
    if (t < 32) {
        float s2 = 0.f;
        #pragma unroll
        for (int i = 0; i < 8; ++i) s2 += ksp[t * 8 + i];
        part[rec + 1024 + t] = s2;
    }
}

// ============ Kernel 5: reduce 64 records -> 4 per bh ============
__global__ __launch_bounds__(256) void reduce1(const float* __restrict__ part,
                                               float* __restrict__ part2) {
    int chunk = blockIdx.x, bh = blockIdx.y, t = threadIdx.x;
    const float* p = part + ((size_t)bh * 64 + chunk * 16) * 1056;
    for (int i = t; i < 1056; i += 256) {
        float s = 0.f;
        #pragma unroll
        for (int j = 0; j < 16; ++j) s += p[(size_t)j * 1056 + i];
        part2[((size_t)bh * 4 + chunk) * 1056 + i] = s;
    }
}

// ============ Kernel 6: build A (bf16) + finalize ksum ============
__global__ __launch_bounds__(256) void build_A(const float* __restrict__ w_out,
                                               const float* __restrict__ part2,
                                               unsigned short* __restrict__ Amat,
                                               float* __restrict__ ksum_g) {
    int ot = blockIdx.x, b = blockIdx.y, t = threadIdx.x;
    __shared__ float cs[NHEAD * HD * HD];
    for (int i = t; i < NHEAD * HD * HD; i += 256) {
        int hh = i >> 10, de = i & 1023;
        const float* p2 = part2 + (size_t)(b * NHEAD + hh) * 4 * 1056;
        float s = 0.f;
        #pragma unroll
        for (int c4 = 0; c4 < 4; ++c4) s += p2[(size_t)c4 * 1056 + de];
        cs[i] = s;
    }
    if (ot == 0) {
        const float* p2 = part2 + (size_t)(b * NHEAD + (t >> 5)) * 4 * 1056;
        float s = 0.f;
        #pragma unroll
        for (int c4 = 0; c4 < 4; ++c4) s += p2[(size_t)c4 * 1056 + 1024 + (t & 31)];
        ksum_g[b * CC + t] = s;
    }
    __syncthreads();
    int h = t >> 5, d = t & 31;
    for (int oi = 0; oi < 32; ++oi) {
        int o = ot * 32 + oi;
        const float* wrow = w_out + (size_t)o * CC + h * HD;
        float s = 0.f;
        #pragma unroll
        for (int e = 0; e < HD; ++e) s += wrow[e] * cs[h * 1024 + d * 32 + e];
        Amat[((size_t)(b * CC + o)) * CC + t] = f2b(s);
    }
}

// ============ Kernel 7: den (R4 verbatim) ============
__global__ __launch_bounds__(256) void den_kernel(const unsigned short* __restrict__ qm_t,
                                                  const float* __restrict__ ksum,
                                                  float* __restrict__ den) {
    int nt = blockIdx.x, h = blockIdx.y, b = blockIdx.z, t = threadIdx.x;
    __shared__ float ks[32];
    if (t < 32) ks[t] = ksum[(b * NHEAD + h) * 32 + t];
    __syncthreads();
    int n = nt * 256 + t;
    const uint4* rp = (const uint4*)(qm_t + ((size_t)(b * NHEAD + h) * NNTOK + n) * 32);
    float s = 0.f;
    #pragma unroll
    for (int i = 0; i < 4; ++i) {
        uint4 u = rp[i];
        s += b2f(u.x & 0xffff) * ks[i * 8 + 0] + b2f(u.x >> 16) * ks[i * 8 + 1];
        s += b2f(u.y & 0xffff) * ks[i * 8 + 2] + b2f(u.y >> 16) * ks[i * 8 + 3];
        s += b2f(u.z & 0xffff) * ks[i * 8 + 4] + b2f(u.z >> 16) * ks[i * 8 + 5];
        s += b2f(u.w & 0xffff) * ks[i * 8 + 6] + b2f(u.w >> 16) * ks[i * 8 + 7];
    }
    den[(size_t)(b * NHEAD + h) * NNTOK + n] = 1.0f / (s + ATT_EPS);
}

// ============ Kernel 8: out = A @ (qm*den) + b_out + x (R4 verbatim) ============
#define LDSF_A   0
#define LDSF_Q   10240
#define LDSF_DEN 20480
#define LDSF_BO  20992
__global__ __launch_bounds__(256, 2) void final_out(
    const unsigned short* __restrict__ qm_t, const unsigned short* __restrict__ Amat,
    const float* __restrict__ den, const float* __restrict__ b_out,
    const float* __restrict__ x, float* __restrict__ out) {
    __shared__ char L[21504];
    int tile = blockIdx.x, mt = blockIdx.y, b = blockIdx.z;
    int n0 = tile * 128, t = threadIdx.x;
    int lane = t & 63, w = t >> 6, lr = lane & 15, lq = lane >> 4;
    int wm = (w >> 1) * 64, wn = (w & 1) * 64;
    accf4 acc[4][4];
    #pragma unroll
    for (int i = 0; i < 4; ++i)
        #pragma unroll
        for (int j = 0; j < 4; ++j) acc[i][j] = (accf4){0.f, 0.f, 0.f, 0.f};

    if (t < 128) ((float*)(L + LDSF_BO))[t] = b_out[mt * 128 + t];

    char* Al = L + LDSF_A;
    char* Ql = L + LDSF_Q;
    for (int h = 0; h < NHEAD; ++h) {
        int m = t >> 1, half = t & 1;
        const char* ag = (const char*)(Amat + ((size_t)(b * CC + mt * 128 + m) * CC + h * 32)) + half * 32;
        float4 av0 = *(const float4*)ag, av1 = *(const float4*)(ag + 16);
        const char* qg = (const char*)(qm_t + ((size_t)(b * NHEAD + h) * NNTOK + n0 + m) * 32) + half * 32;
        float4 qv0 = *(const float4*)qg, qv1 = *(const float4*)(qg + 16);
        float dv = 0.f;
        if (t < 128) dv = den[(size_t)(b * NHEAD + h) * NNTOK + n0 + t];
        __syncthreads();
        *(float4*)(Al + m * 80 + half * 32) = av0;
        *(float4*)(Al + m * 80 + half * 32 + 16) = av1;
        *(float4*)(Ql + m * 80 + half * 32) = qv0;
        *(float4*)(Ql + m * 80 + half * 32 + 16) = qv1;
        if (t < 128) ((float*)(L + LDSF_DEN))[t] = dv;
        __syncthreads();
        {
            int n = t >> 1, u = t & 1;
            float dn = ((float*)(L + LDSF_DEN))[n];
            char* p = Ql + n * 80 + u * 32;
            bfrag8 v0 = *(bfrag8*)p, v1 = *(bfrag8*)(p + 16);
            #pragma unroll
            for (int e = 0; e < 8; ++e) {
                v0[e] = (short)f2b(b2f((unsigned short)v0[e]) * dn);
                v1[e] = (short)f2b(b2f((unsigned short)v1[e]) * dn);
            }
            *(bfrag8*)p = v0;
            *(bfrag8*)(p + 16) = v1;
        }
        __syncthreads();
        bfrag8 bfr[4];
        #pragma unroll
        for (int ci = 0; ci < 4; ++ci) {
            int n = wn + ci * 16 + lr;
            bfr[ci] = *(const bfrag8*)(Ql + n * 80 + lq * 16);
        }
        #pragma unroll
        for (int mi = 0; mi < 4; ++mi) {
            bfrag8 a = *(const bfrag8*)(Al + (wm + mi * 16 + lr) * 80 + lq * 16);
            #pragma unroll
            for (int ci = 0; ci < 4; ++ci)
                acc[mi][ci] = __builtin_amdgcn_mfma_f32_16x16x32_bf16(a, bfr[ci], acc[mi][ci], 0, 0, 0);
        }
        __syncthreads();
    }

    const float* bo_s = (const float*)(L + LDSF_BO);
    #pragma unroll
    for (int mi = 0; mi < 4; ++mi)
        #pragma unroll
        for (int ci = 0; ci < 4; ++ci)
            #pragma unroll
            for (int r = 0; r < 4; ++r) {
                int ol = wm + mi * 16 + lq * 4 + r;
                int n = wn + ci * 16 + lr;
                size_t idx = ((size_t)(b * CC + mt * 128 + ol)) * NNTOK + n0 + n;
                out[idx] = acc[mi][ci][r] + bo_s[ol] + x[idx];
            }
}

extern "C" void kernel_launch(void* const* d_in, const int* in_sizes, int n_in,
                              void* d_out, int out_size, void* d_ws, size_t ws_size,
                              hipStream_t stream) {
    (void)in_sizes; (void)n_in; (void)out_size; (void)ws_size;
    const float* x      = (const float*)d_in[0];
    const float* gamma  = (const float*)d_in[1];
    const float* beta   = (const float*)d_in[2];
    const float* wq     = (const float*)d_in[3];
    const float* wk     = (const float*)d_in[4];
    const float* wv     = (const float*)d_in[5];
    const float* w_out  = (const float*)d_in[6];
    const float* b_out  = (const float*)d_in[7];
    float* out = (float*)d_out;
    float* ws  = (float*)d_ws;

    unsigned short* qm_t = (unsigned short*)(ws + WS_QMT);
    unsigned short* xt_g = (unsigned short*)(ws + WS_XNT);
    unsigned short* Wst  = (unsigned short*)(ws + WS_WST);
    float* biasg = ws + WS_BIAS;
    float* part  = ws + WS_PART;
    float* part2 = ws + WS_PART2;
    float* gnp   = ws + WS_GNP;
    float* scale = ws + WS_SCALE;
    float* shift = ws + WS_SHIFT;
    float* ksum  = ws + WS_KSUM;
    unsigned short* Amat = (unsigned short*)(ws + WS_AMAT);
    float* den   = ws + WS_DEN;   // aliases part head (part dead after reduce1)

    hipLaunchKernelGGL(xt_gn, dim3(NNTOK / 64, BB), dim3(256), 0, stream, x, xt_g, gnp);
    hipLaunchKernelGGL(gn_finalize, dim3(1), dim3(256), 0, stream, gnp, gamma, beta, scale, shift);
    hipLaunchKernelGGL(prep_w, dim3(NHEAD, BB), dim3(256), 0, stream,
                       wq, wk, wv, scale, shift, Wst, biasg);
    hipLaunchKernelGGL(qkv_ctx, dim3(64, NHEAD, BB), dim3(256), 0, stream,
                       xt_g, Wst, biasg, qm_t, part);
    hipLaunchKernelGGL(reduce1, dim3(4, 16), dim3(256), 0, stream, part, part2);
    hipLaunchKernelGGL(build_A, dim3(8, BB), dim3(256), 0, stream, w_out, part2, Amat, ksum);
    hipLaunchKernelGGL(den_kernel, dim3(NNTOK / 256, NHEAD, BB), dim3(256), 0, stream,
                       qm_t, ksum, den);
    hipLaunchKernelGGL(final_out, dim3(NNTOK / 128, 2, BB), dim3(256), 0, stream,
                       qm_t, Amat, den, b_out, x, out);
}